// Round 2
// baseline (614.591 us; speedup 1.0000x reference)
//
#include <hip/hip_runtime.h>

// FFT depthwise conv3d with KT=1 == depthwise 7x7 CIRCULAR conv over (H,W),
// independent per (b,t,c).  out[h,w,c] = sum_{dh,dw} k[c,dh,dw]*x[(h+3-dh)%H,(w+3-dw)%W,c]
// Layout: x (B,T,H,W,C) channels-last, C=96 -> float4 over channel quads (24 per pixel).

#define BT   16    // B*T
#define HH   224
#define WW   224
#define CC   96
#define C4   24    // CC/4
#define KW   7
#define TAPS 49

__device__ __forceinline__ void fma4(float4& a, const float4 b, const float4 w) {
    a.x = fmaf(b.x, w.x, a.x);
    a.y = fmaf(b.y, w.y, a.y);
    a.z = fmaf(b.z, w.z, a.z);
    a.w = fmaf(b.w, w.w, a.w);
}

__global__ __launch_bounds__(256) void dwconv7x7_circ(
        const float4* __restrict__ x,     // (BT,H,W,C4) float4
        const float*  __restrict__ kern,  // (C, 1, 7, 7)
        float4* __restrict__ out) {
    // Weights transposed into LDS: wlds[tap*C4 + c4] = float4 of channels 4*c4..+3 at tap.
    __shared__ float4 wlds[TAPS * C4];
    {
        float* wf = (float*)wlds;
        for (int i = threadIdx.x; i < TAPS * CC; i += 256) {
            int c   = i % CC;        // dst: tap-major, channel fastest (conflict-free write)
            int tap = i / CC;
            wf[i] = kern[c * TAPS + tap];
        }
    }
    __syncthreads();

    int gid = blockIdx.x * 256 + threadIdx.x;
    int c4 = gid % C4;
    int r  = gid / C4;
    int w4 = r % 56;          // 4-wide w block
    int r2 = r / 56;
    int h2 = r2 % 112;        // 2-tall h block
    int bt = r2 / 112;
    int w0 = w4 * 4;
    int h0 = h2 * 2;

    // Wrapped column float4-offsets within a row: ww = w0-3+i, i in [0,10)
    int wc[10];
#pragma unroll
    for (int i = 0; i < 10; ++i) {
        int ww = w0 - 3 + i;
        if (ww < 0) ww += WW;
        if (ww >= WW) ww -= WW;
        wc[i] = ww * C4 + c4;
    }
    // Wrapped input rows: hh = h0-3+j, j in [0,8)
    int hrow[8];
#pragma unroll
    for (int j = 0; j < 8; ++j) {
        int hh = h0 - 3 + j;
        if (hh < 0) hh += HH;
        if (hh >= HH) hh -= HH;
        hrow[j] = hh;
    }

    const float4* xbt = x + (size_t)bt * (HH * WW * C4);

    float4 acc0[4], acc1[4];
#pragma unroll
    for (int p = 0; p < 4; ++p) {
        acc0[p] = make_float4(0.f, 0.f, 0.f, 0.f);
        acc1[p] = make_float4(0.f, 0.f, 0.f, 0.f);
    }

#pragma unroll
    for (int j = 0; j < 8; ++j) {
        const float4* row = xbt + (size_t)hrow[j] * (WW * C4);
        float4 in[10];
#pragma unroll
        for (int i = 0; i < 10; ++i) in[i] = row[wc[i]];

        // output row h0 uses input row hh = h0+3-dh  ->  dh = 6 - j  (valid j<=6)
        if (j <= 6) {
            const int dh = 6 - j;
#pragma unroll
            for (int dw = 0; dw < KW; ++dw) {
                float4 wt = wlds[(dh * KW + dw) * C4 + c4];
#pragma unroll
                for (int p = 0; p < 4; ++p)
                    fma4(acc0[p], in[p + 6 - dw], wt);
            }
        }
        // output row h0+1: dh = 7 - j  (valid j>=1)
        if (j >= 1) {
            const int dh = 7 - j;
#pragma unroll
            for (int dw = 0; dw < KW; ++dw) {
                float4 wt = wlds[(dh * KW + dw) * C4 + c4];
#pragma unroll
                for (int p = 0; p < 4; ++p)
                    fma4(acc1[p], in[p + 6 - dw], wt);
            }
        }
    }

    float4* obt = out + (size_t)bt * (HH * WW * C4);
#pragma unroll
    for (int p = 0; p < 4; ++p) {
        obt[((size_t)h0 * WW + (w0 + p)) * C4 + c4]       = acc0[p];
        obt[((size_t)(h0 + 1) * WW + (w0 + p)) * C4 + c4] = acc1[p];
    }
}

extern "C" void kernel_launch(void* const* d_in, const int* in_sizes, int n_in,
                              void* d_out, int out_size, void* d_ws, size_t ws_size,
                              hipStream_t stream) {
    const float* x    = (const float*)d_in[0];   // (2,8,224,224,96) fp32
    const float* kern = (const float*)d_in[1];   // (96,1,7,7) fp32
    float* out = (float*)d_out;                  // fp32, same shape as x

    // threads: C4(24) * 56(w blocks) * 112(h blocks) * 16(bt) = 2,408,448 = 9408 * 256
    const int nblocks = (C4 * 56 * 112 * BT) / 256;
    dwconv7x7_circ<<<nblocks, 256, 0, stream>>>(
        (const float4*)x, kern, (float4*)out);
}